// Round 8
// baseline (37.790 us; speedup 1.0000x reference)
//
#include <hip/hip_runtime.h>
#include <math.h>

#define IN_DIMS 128
#define OUT_PER_B (IN_DIMS * 9)

typedef float f4 __attribute__((ext_vector_type(4)));  // nt builtins need native vec

// R5 structure (one-shot block per element, single barrier) + NONTEMPORAL hints:
// x is streamed once (128 MB) and out never re-read, so bypass cache allocation
// on both streams (gfx950 'nt' modifier).
// t -> c = t>>2 (channel), s = t&3 (quarter). Load k: float4 at byte offset
// 16*s + 64*k of channel c => lanes 4c..4c+3 cover whole 64-B lines (1 req/line).
// emb[3a+cc][h][w] = A[a][w]*B[cc][h] exactly (von-Mises x gaussian separable);
// A[a][w]=emb[3a][0][w], B[cc][h]=emb[cc][h][0] scales outputs by emb[0][0][0]>0,
// which cancels in the L2 norm.
__global__ __launch_bounds__(512) void ese_kernel(
        const float* __restrict__ x,     // (B, 128, 8, 8)
        const float* __restrict__ emb,   // (9, 8, 8)
        float* __restrict__ out)         // (B, 1152)
{
    __shared__ float s_out[OUT_PER_B];   // unnormalized, read back as f4
    __shared__ float s_red[8];           // per-wave ss partials

    const int b = blockIdx.x;
    const int t = threadIdx.x;
    const int c = t >> 2;            // channel 0..127
    const int s = t & 3;             // quarter 0..3
    const int wb = (s & 1) * 4;      // w-base: 0 or 4
    const int hb = s >> 1;           // h = 2k + hb

    // Streaming loads first (in flight during emb setup) — nontemporal.
    const f4* __restrict__ xp =
        reinterpret_cast<const f4*>(x + ((size_t)b * IN_DIMS + c) * 64);
    f4 v[4];
#pragma unroll
    for (int k = 0; k < 4; ++k) v[k] = __builtin_nontemporal_load(&xp[s + 4 * k]);

    // emb constant slices -> registers (24 dwords, reused by every block: keep cached).
    f4 sAv[3];
#pragma unroll
    for (int a = 0; a < 3; ++a)
        sAv[a] = *reinterpret_cast<const f4*>(&emb[(3 * a) * 64 + wb]);
    float sBv[3][4];
#pragma unroll
    for (int cc = 0; cc < 3; ++cc)
#pragma unroll
        for (int k = 0; k < 4; ++k)
            sBv[cc][k] = emb[cc * 64 + (2 * k + hb) * 8];

    float acc[9];
#pragma unroll
    for (int j = 0; j < 9; ++j) acc[j] = 0.0f;

#pragma unroll
    for (int k = 0; k < 4; ++k) {
#pragma unroll
        for (int a = 0; a < 3; ++a) {
            const float u = v[k].x * sAv[a].x + v[k].y * sAv[a].y
                          + v[k].z * sAv[a].z + v[k].w * sAv[a].w;
#pragma unroll
            for (int cc = 0; cc < 3; ++cc)
                acc[3 * a + cc] += u * sBv[cc][k];
        }
    }

    // Merge the 4 quarter-lanes of each channel (xor 1,2 are cheap DPP quad-perms).
#pragma unroll
    for (int off = 1; off <= 2; off <<= 1)
#pragma unroll
        for (int j = 0; j < 9; ++j)
            acc[j] += __shfl_xor(acc[j], off, 64);

    // Stage unnormalized outputs (writer lane s==0; dword stride 9 conflict-free).
    if (s == 0) {
#pragma unroll
        for (int j = 0; j < 9; ++j) s_out[c * 9 + j] = acc[j];
    }

    // Block-wide sum-of-squares partials.
    float ss = 0.0f;
#pragma unroll
    for (int j = 0; j < 9; ++j) ss += acc[j] * acc[j];
#pragma unroll
    for (int off = 4; off <= 32; off <<= 1)
        ss += __shfl_xor(ss, off, 64);
    if ((t & 63) == 0) s_red[t >> 6] = ss;

    __syncthreads();   // the ONLY barrier

    const f4 r0 = reinterpret_cast<const f4*>(s_red)[0];
    const f4 r1 = reinterpret_cast<const f4*>(s_red)[1];
    const float total = ((r0.x + r0.y) + (r0.z + r0.w))
                      + ((r1.x + r1.y) + (r1.z + r1.w));
    const float rn = 1.0f / sqrtf(total + 1e-10f);

    // Normalize at read time; 288 contiguous float4 stores — nontemporal.
    f4* __restrict__ ob4 = reinterpret_cast<f4*>(out + (size_t)b * OUT_PER_B);
    if (t < OUT_PER_B / 4) {
        f4 o = reinterpret_cast<const f4*>(s_out)[t];
        o *= rn;
        __builtin_nontemporal_store(o, &ob4[t]);
    }
}

extern "C" void kernel_launch(void* const* d_in, const int* in_sizes, int n_in,
                              void* d_out, int out_size, void* d_ws, size_t ws_size,
                              hipStream_t stream) {
    const float* x   = (const float*)d_in[0];
    const float* emb = (const float*)d_in[1];
    float* out       = (float*)d_out;

    const int B = in_sizes[0] / (IN_DIMS * 64);   // 4096
    ese_kernel<<<B, 512, 0, stream>>>(x, emb, out);
}

// Round 9
// 28.527 us; speedup vs baseline: 1.3247x; 1.3247x over previous
//
#include <hip/hip_runtime.h>
#include <math.h>

#define IN_DIMS 128
#define OUT_PER_B (IN_DIMS * 9)

// BEST measured structure (R2, 27.9 us ~= 5.5 TB/s effective):
// Block = 512 threads = one batch element; independent one-shot blocks pipeline
// best (persistent/EPB/2-elem/nt variants all measured slower or equal).
// t -> c = t>>2 (channel), s = t&3 (quarter). Load k: float4 at byte offset
// 16*s + 64*k of channel c => lanes 4c..4c+3 cover whole 64-B lines (1 req/line).
// emb[3a+cc][h][w] = A[a][w]*B[cc][h] exactly (von-Mises x gaussian separable);
// A[a][w]=emb[3a][0][w], B[cc][h]=emb[cc][h][0] scales outputs by emb[0][0][0]>0,
// which cancels in the L2 norm.
__global__ __launch_bounds__(512) void ese_kernel(
        const float* __restrict__ x,     // (B, 128, 8, 8)
        const float* __restrict__ emb,   // (9, 8, 8)
        float* __restrict__ out)         // (B, 1152)
{
    __shared__ float s_out[OUT_PER_B];
    __shared__ float s_red[8];

    const int b = blockIdx.x;
    const int t = threadIdx.x;
    const int c = t >> 2;            // channel 0..127
    const int s = t & 3;             // quarter 0..3
    const int wb = (s & 1) * 4;      // w-base: 0 or 4
    const int hb = s >> 1;           // h = 2k + hb

    // Streaming loads first (in flight during emb setup).
    const float4* __restrict__ xp =
        reinterpret_cast<const float4*>(x + ((size_t)b * IN_DIMS + c) * 64);
    float4 v[4];
#pragma unroll
    for (int k = 0; k < 4; ++k) v[k] = xp[s + 4 * k];

    // emb constant slices -> registers (24 dwords, L1/L2-resident).
    float4 sAv[3];
#pragma unroll
    for (int a = 0; a < 3; ++a)
        sAv[a] = *reinterpret_cast<const float4*>(&emb[(3 * a) * 64 + wb]);
    float sBv[3][4];
#pragma unroll
    for (int cc = 0; cc < 3; ++cc)
#pragma unroll
        for (int k = 0; k < 4; ++k)
            sBv[cc][k] = emb[cc * 64 + (2 * k + hb) * 8];

    float acc[9];
#pragma unroll
    for (int j = 0; j < 9; ++j) acc[j] = 0.0f;

#pragma unroll
    for (int k = 0; k < 4; ++k) {
#pragma unroll
        for (int a = 0; a < 3; ++a) {
            const float u = v[k].x * sAv[a].x + v[k].y * sAv[a].y
                          + v[k].z * sAv[a].z + v[k].w * sAv[a].w;
#pragma unroll
            for (int cc = 0; cc < 3; ++cc)
                acc[3 * a + cc] += u * sBv[cc][k];
        }
    }

    // Merge the 4 quarter-lanes of each channel (xor 1,2 are cheap DPP quad-perms).
#pragma unroll
    for (int off = 1; off <= 2; off <<= 1)
#pragma unroll
        for (int j = 0; j < 9; ++j)
            acc[j] += __shfl_xor(acc[j], off, 64);

    // Block-wide sum of squares: per-group ss identical on the 4 lanes; reduce
    // across the 16 groups of the wave, then across the 8 waves via LDS.
    float ss = 0.0f;
#pragma unroll
    for (int j = 0; j < 9; ++j) ss += acc[j] * acc[j];
#pragma unroll
    for (int off = 4; off <= 32; off <<= 1)
        ss += __shfl_xor(ss, off, 64);
    if ((t & 63) == 0) s_red[t >> 6] = ss;
    __syncthreads();
    float total = 0.0f;
#pragma unroll
    for (int r = 0; r < 8; ++r) total += s_red[r];
    const float rn = 1.0f / sqrtf(total + 1e-10f);

    // Stage normalized outputs (writer lane s==0; dword stride 9 conflict-free),
    // then coalesced float4 store.
    if (s == 0) {
#pragma unroll
        for (int j = 0; j < 9; ++j) s_out[c * 9 + j] = acc[j] * rn;
    }
    __syncthreads();

    float4* __restrict__ ob4 = reinterpret_cast<float4*>(out + (size_t)b * OUT_PER_B);
    if (t < OUT_PER_B / 4)
        ob4[t] = reinterpret_cast<const float4*>(s_out)[t];
}

extern "C" void kernel_launch(void* const* d_in, const int* in_sizes, int n_in,
                              void* d_out, int out_size, void* d_ws, size_t ws_size,
                              hipStream_t stream) {
    const float* x   = (const float*)d_in[0];
    const float* emb = (const float*)d_in[1];
    float* out       = (float*)d_out;

    const int B = in_sizes[0] / (IN_DIMS * 64);   // 4096
    ese_kernel<<<B, 512, 0, stream>>>(x, emb, out);
}